// Round 2
// baseline (431.638 us; speedup 1.0000x reference)
//
#include <hip/hip_runtime.h>

// FWHT of 16384 rows x 4096 fp32, times scalar scale.
// v3: same 256-thr/4-wave/1-row shape as v2, but all LDS traffic is b128 and
// all global stores are dwordx4. Achieved by keeping element bits {0,1} in
// registers through BOTH transposes and moving the displaced butterflies
// (element bits {2,3} and {6,7}) onto DPP quad_perm cross-lane ops (pure
// VALU, no LDS pipe, no barriers).
//
// Pass structure (12 bits, each butterflied exactly once):
//   P1: bits {0,1}  (float4 components) + {10,11} (k regs)     [in-reg]
//   P2: bits {4,5}  (reg index q)        in-reg
//       bits {2,3}  (lane bits 0,1)      DPP quad_perm xor1/xor2
//   P3: bits {8,9}  (reg index q)        in-reg
//       bits {6,7}  (lane bits 0,1)      DPP quad_perm xor1/xor2
//
// LDS layout: elem i at word A(i) = i + 4*(i>>6) (64-word rows padded to 68).
// T1w: 4x ds_write_b128; T1r/T2w/T2r: 4x b128 each (16 b128 total, was
// 4 b128 + 48 b32). All b128 access sets are bank-balanced (8 words/bank,
// the LDS minimum for 256-word ops). T1r and T2w use identical per-thread
// addresses -> only 2 barriers.
// Epilogue: 4x global_store_dwordx4, each 1KB-contiguous per wave.

__device__ __forceinline__ void bfly(float& a, float& b) {
  const float x = a, y = b;
  a = x + y; b = x - y;
}

// Quad-perm lane swap: CTRL=0xB1 is perm[1,0,3,2] (lane xor 1),
// CTRL=0x4E is perm[2,3,0,1] (lane xor 2).
template <int CTRL>
__device__ __forceinline__ float qswap(float v) {
  return __int_as_float(
      __builtin_amdgcn_mov_dpp(__float_as_int(v), CTRL, 0xF, 0xF, true));
}

__global__ __launch_bounds__(256, 8) void fwht_kernel(
    const float* __restrict__ x, const float* __restrict__ scale,
    float* __restrict__ out) {
  __shared__ __align__(16) float lds[4348];  // 3*1088 + 1084 words
  const int t = threadIdx.x;   // 0..255
  const int row = blockIdx.x;  // 0..16383
  const float* xr = x + (size_t)row * 4096;
  float* outr = out + (size_t)row * 4096;
  const float s = scale[0];

  // per-lane butterfly signs for the DPP passes (lane bit 0 / bit 1)
  const float sg1 = (t & 1) ? -1.0f : 1.0f;
  const float sg2 = (t & 2) ? -1.0f : 1.0f;

  float r[16];

  // ---- load: r[k*4+c] = x[k*1024 + 4t + c] — 4 dense float4/thread ----
#pragma unroll
  for (int k = 0; k < 4; ++k) {
    const float4 f = *reinterpret_cast<const float4*>(xr + k * 1024 + 4 * t);
    r[k * 4 + 0] = f.x; r[k * 4 + 1] = f.y;
    r[k * 4 + 2] = f.z; r[k * 4 + 3] = f.w;
  }

  // ---- P1: butterflies on bits 0,1 (c) and 10,11 (k) ----
#pragma unroll
  for (int k = 0; k < 4; ++k) {
    bfly(r[k * 4 + 0], r[k * 4 + 1]); bfly(r[k * 4 + 2], r[k * 4 + 3]); // bit0
    bfly(r[k * 4 + 0], r[k * 4 + 2]); bfly(r[k * 4 + 1], r[k * 4 + 3]); // bit1
  }
#pragma unroll
  for (int c = 0; c < 4; ++c) {
    bfly(r[0 + c], r[4 + c]); bfly(r[8 + c], r[12 + c]);                // bit10
    bfly(r[0 + c], r[8 + c]); bfly(r[4 + c], r[12 + c]);                // bit11
  }

  // ---- T1 write: elem i = k*1024 + 4t + c -> A(i); 4x b128 ----
  {
    const int wb = 4 * t + 4 * (t >> 4);
#pragma unroll
    for (int k = 0; k < 4; ++k) {
      *reinterpret_cast<float4*>(&lds[k * 1088 + wb]) =
          make_float4(r[k * 4 + 0], r[k * 4 + 1], r[k * 4 + 2], r[k * 4 + 3]);
    }
  }
  __syncthreads();

  // ---- T1 read: regs <- bits {0,1,4,5}; lanes: bits{2,3}=t&3,
  //      bits{6..9}=(t>>2)&15, bits{10,11}=t>>6. 4x b128. ----
  const int rb1 = 4 * (t & 3) + 68 * ((t >> 2) & 15) + 1088 * (t >> 6);
#pragma unroll
  for (int q = 0; q < 4; ++q) {
    const float4 f = *reinterpret_cast<const float4*>(&lds[rb1 + 16 * q]);
    r[q * 4 + 0] = f.x; r[q * 4 + 1] = f.y;
    r[q * 4 + 2] = f.z; r[q * 4 + 3] = f.w;
  }

  // ---- P2: bits 4,5 in regs; bits 2,3 via DPP quad_perm ----
#pragma unroll
  for (int c = 0; c < 4; ++c) {
    bfly(r[0 + c], r[4 + c]); bfly(r[8 + c], r[12 + c]);                // bit4
    bfly(r[0 + c], r[8 + c]); bfly(r[4 + c], r[12 + c]);                // bit5
  }
#pragma unroll
  for (int i = 0; i < 16; ++i) r[i] = fmaf(sg1, r[i], qswap<0xB1>(r[i])); // bit2
#pragma unroll
  for (int i = 0; i < 16; ++i) r[i] = fmaf(sg2, r[i], qswap<0x4E>(r[i])); // bit3

  // ---- T2 write: same per-thread addresses as T1 read (own words only,
  //      no barrier needed in between). 4x b128. ----
#pragma unroll
  for (int q = 0; q < 4; ++q) {
    *reinterpret_cast<float4*>(&lds[rb1 + 16 * q]) =
        make_float4(r[q * 4 + 0], r[q * 4 + 1], r[q * 4 + 2], r[q * 4 + 3]);
  }
  __syncthreads();

  // ---- T2 read: regs <- bits {0,1,8,9}; lanes: bits{6,7}=t&3,
  //      bits{2..5}=(t>>2)&15, bits{10,11}=t>>6. 4x b128. ----
  const int rb2 = 4 * ((t >> 2) & 15) + 68 * (t & 3) + 1088 * (t >> 6);
#pragma unroll
  for (int q = 0; q < 4; ++q) {
    const float4 f = *reinterpret_cast<const float4*>(&lds[rb2 + 272 * q]);
    r[q * 4 + 0] = f.x; r[q * 4 + 1] = f.y;
    r[q * 4 + 2] = f.z; r[q * 4 + 3] = f.w;
  }

  // ---- P3: bits 8,9 in regs; bits 6,7 via DPP quad_perm ----
#pragma unroll
  for (int c = 0; c < 4; ++c) {
    bfly(r[0 + c], r[4 + c]); bfly(r[8 + c], r[12 + c]);                // bit8
    bfly(r[0 + c], r[8 + c]); bfly(r[4 + c], r[12 + c]);                // bit9
  }
#pragma unroll
  for (int i = 0; i < 16; ++i) r[i] = fmaf(sg1, r[i], qswap<0xB1>(r[i])); // bit6
#pragma unroll
  for (int i = 0; i < 16; ++i) r[i] = fmaf(sg2, r[i], qswap<0x4E>(r[i])); // bit7

  // ---- scale + store: 4x dwordx4, 1KB contiguous per wave-instruction ----
  float* ob = outr + 4 * ((t >> 2) & 15) + 64 * (t & 3) + 1024 * (t >> 6);
#pragma unroll
  for (int q = 0; q < 4; ++q) {
    *reinterpret_cast<float4*>(ob + 256 * q) =
        make_float4(r[q * 4 + 0] * s, r[q * 4 + 1] * s,
                    r[q * 4 + 2] * s, r[q * 4 + 3] * s);
  }
}

extern "C" void kernel_launch(void* const* d_in, const int* in_sizes, int n_in,
                              void* d_out, int out_size, void* d_ws, size_t ws_size,
                              hipStream_t stream) {
  (void)in_sizes; (void)n_in; (void)d_ws; (void)ws_size; (void)out_size;
  const float* x = (const float*)d_in[0];
  const float* scale = (const float*)d_in[1];
  float* out = (float*)d_out;
  fwht_kernel<<<16384, 256, 0, stream>>>(x, scale, out);
}